// Round 7
// baseline (6296.233 us; speedup 1.0000x reference)
//
#include <hip/hip_runtime.h>

// LSTM: B=64, T=1024, IN=256, H=512, gates=2048; then Linear 512->512.
// Inputs (fp32): x, h0, c0, w_lstm[768,2048], b_lstm[2048], w_lin[512,512], b_lin[512]
// Output (fp32): y[64,1024,512] ++ h_fin[64,512] ++ c_fin[64,512]
//
// 256 WGs (1/CU): 8 batch-groups (8 rows, bg=bid&7) x 32 col-groups (16 h-cols).
// Sentinel sync (data IS the flag; 0x7F7F unreachable since |h|<1), XCD-local
// L2 on the runtime-verified fast path, MALL fallback otherwise.
// R7: ONLY WAVE 0 SPINS (compact 8KB cover); after detect + barrier all waves
// load h once (verified clean). y store deferred to post-poll (keeps HBM store
// latency out of the poll's vmcnt(0)).

#define BB   64
#define TT   1024
#define DIN  256
#define HH   512
#define OUTD 512
#define NWG  256
#define YTOT (BB*TT*OUTD)
#define SENT 0x7F7F7F7Fu

typedef __attribute__((ext_vector_type(4))) float f32x4;
typedef __attribute__((ext_vector_type(2))) float f32x2;
typedef __attribute__((ext_vector_type(4))) unsigned u32x4;
typedef __attribute__((ext_vector_type(8))) short short8;

__device__ inline short f2bf(float f) {
    unsigned u = __float_as_uint(f);
    unsigned r = u + 0x7fffu + ((u >> 16) & 1u);   // RNE
    return (short)(r >> 16);
}
__device__ inline float sigf(float x) { return 1.0f / (1.0f + __expf(-x)); }
__device__ inline float tanhfast(float x) { return 1.0f - 2.0f / (__expf(2.0f * x) + 1.0f); }

__device__ inline short8 pack8(f32x4 lo, f32x4 hi) {
    short8 a;
    a[0] = f2bf(lo[0]); a[1] = f2bf(lo[1]); a[2] = f2bf(lo[2]); a[3] = f2bf(lo[3]);
    a[4] = f2bf(hi[0]); a[5] = f2bf(hi[1]); a[6] = f2bf(hi[2]); a[7] = f2bf(hi[3]);
    return a;
}

#define MFMA(a, b, c) __builtin_amdgcn_mfma_f32_16x16x32_bf16((a), (b), (c), 0, 0, 0)

// x-part of the gate GEMM for one timestep: 8 MFMAs, K=[0,256).
__device__ inline void xpart(f32x4 acc[4], const float* __restrict__ x, int arow, int t, int kq,
                             const short8* bf) {
    const float* xp = x + ((size_t)arow * TT + t) * DIN + kq * 8;
    #pragma unroll
    for (int kk = 0; kk < 8; ++kk) {
        f32x4 lo = *(const f32x4*)(xp + kk * 32);
        f32x4 hi = *(const f32x4*)(xp + kk * 32 + 4);
        acc[kk & 3] = MFMA(pack8(lo, hi), bf[kk], acc[kk & 3]);
    }
}

template<bool LOCAL>
__device__ inline void lstm_loop(const float* __restrict__ x, const float* __restrict__ h0,
                                 const float* __restrict__ c0, float* __restrict__ out,
                                 unsigned short* __restrict__ hbuf,
                                 const short8* bf, float bias, int bg, int cg,
                                 float (*gates)[16][17])
{
    const int tid  = threadIdx.x;
    const int w    = tid >> 6;
    const int lane = tid & 63;
    const int nl   = lane & 15;
    const int kq   = lane >> 4;

    // Elementwise mapping: wave 0 (tid<64) owns (row 0..7, col-pair 0..7).
    const bool ew   = (tid < 64);
    const int ebl   = (tid >> 3) & 7;
    const int ej2   = tid & 7;
    const int ebrow = bg * 8 + ebl;
    const int ecol0 = cg * 16 + ej2 * 2;
    f32x2 creg = {0.f, 0.f};
    if (ew) creg = *(const f32x2*)&c0[(size_t)ebrow * HH + ecol0];

    const int arow = bg * 8 + (nl & 7);    // A rows 8..15 duplicate 0..7

    // Compact poll cover (wave 0): lane covers row (lane>>3), cols (lane&7)*64..+64.
    // Consecutive lanes cover consecutive 16B chunks -> coalesced 128B lines.
    const size_t pslice = (size_t)(bg * 8 + (lane >> 3)) * HH + (size_t)(lane & 7) * 64;

    const f32x4 zero = {0.f, 0.f, 0.f, 0.f};
    f32x4 acc[4] = {zero, zero, zero, zero};
    xpart(acc, x, arow, 0, kq, bf);        // x-part for t=0

    for (int t = 0; t < TT; ++t) {
        // ---- h part: K=[256,768)
        if (t == 0) {
            const float* hp = h0 + (size_t)arow * HH + kq * 8;
            #pragma unroll
            for (int kk = 0; kk < 16; ++kk) {
                f32x4 lo = *(const f32x4*)(hp + kk * 32);
                f32x4 hi = *(const f32x4*)(hp + kk * 32 + 4);
                acc[kk & 3] = MFMA(pack8(lo, hi), bf[8 + kk], acc[kk & 3]);
            }
        } else {
            // Buffer verified sentinel-free by wave 0 before the last barrier.
            const unsigned short* hp = hbuf + ((t - 1) & 3) * (BB * HH) + (size_t)arow * HH + kq * 8;
            short8 ha[16];
            #pragma unroll
            for (int kk = 0; kk < 16; ++kk) {
                if (LOCAL)
                    asm volatile("global_load_dwordx4 %0, %1, off offset:%2 sc0"
                                 : "=&v"(ha[kk]) : "v"(hp), "i"(kk * 64));
                else
                    asm volatile("global_load_dwordx4 %0, %1, off offset:%2 sc0 sc1"
                                 : "=&v"(ha[kk]) : "v"(hp), "i"(kk * 64));
            }
            asm volatile("s_waitcnt vmcnt(0)" ::: "memory");
            __builtin_amdgcn_sched_barrier(0);
            #pragma unroll
            for (int kk = 0; kk < 16; ++kk)
                acc[kk & 3] = MFMA(ha[kk], bf[8 + kk], acc[kk & 3]);
        }

        // ---- gate tile -> LDS (C layout: row=kq*4+r, col=nl; rows 8-15 dup)
        #pragma unroll
        for (int r = 0; r < 4; ++r)
            gates[w][kq * 4 + r][nl] = acc[0][r] + acc[1][r] + acc[2][r] + acc[3][r] + bias;
        __syncthreads();

        if (t == TT - 1) {
            if (ew) {
                float i0 = gates[0][ebl][ej2 * 2], i1 = gates[0][ebl][ej2 * 2 + 1];
                float g0 = gates[1][ebl][ej2 * 2], g1 = gates[1][ebl][ej2 * 2 + 1];
                float f0 = gates[2][ebl][ej2 * 2], f1 = gates[2][ebl][ej2 * 2 + 1];
                float o0 = gates[3][ebl][ej2 * 2], o1 = gates[3][ebl][ej2 * 2 + 1];
                creg[0] = sigf(f0 + 1.0f) * creg[0] + sigf(i0) * tanhfast(g0);
                creg[1] = sigf(f1 + 1.0f) * creg[1] + sigf(i1) * tanhfast(g1);
                f32x2 hv = { sigf(o0) * tanhfast(creg[0]), sigf(o1) * tanhfast(creg[1]) };
                *(f32x2*)&out[((size_t)ebrow * TT + t) * OUTD + ecol0] = hv;
                *(f32x2*)&out[YTOT + (size_t)ebrow * OUTD + ecol0] = hv;               // h_fin
                *(f32x2*)&out[YTOT + BB * OUTD + (size_t)ebrow * OUTD + ecol0] = creg; // c_fin
            }
        } else {
            f32x2 hv = {0.f, 0.f};
            if (ew) {
                float i0 = gates[0][ebl][ej2 * 2], i1 = gates[0][ebl][ej2 * 2 + 1];
                float g0 = gates[1][ebl][ej2 * 2], g1 = gates[1][ebl][ej2 * 2 + 1];
                float f0 = gates[2][ebl][ej2 * 2], f1 = gates[2][ebl][ej2 * 2 + 1];
                float o0 = gates[3][ebl][ej2 * 2], o1 = gates[3][ebl][ej2 * 2 + 1];
                creg[0] = sigf(f0 + 1.0f) * creg[0] + sigf(i0) * tanhfast(g0);
                creg[1] = sigf(f1 + 1.0f) * creg[1] + sigf(i1) * tanhfast(g1);
                hv[0] = sigf(o0) * tanhfast(creg[0]);
                hv[1] = sigf(o1) * tanhfast(creg[1]);

                unsigned hw = (unsigned)(unsigned short)f2bf(hv[0])
                            | ((unsigned)(unsigned short)f2bf(hv[1]) << 16);
                const size_t slot = (size_t)ebrow * HH + ecol0;
                unsigned short* hp = hbuf + (t & 3) * (BB * HH) + slot;
                unsigned short* sp = hbuf + ((t + 2) & 3) * (BB * HH) + slot;
                unsigned sv = SENT;
                // sentinel-reset (buffer reused at t+2) then h publish; both are
                // drained by this wave's first poll vmcnt(0) below.
                if (LOCAL) {
                    asm volatile("global_store_dword %0, %1, off" :: "v"(sp), "v"(sv) : "memory");
                    asm volatile("global_store_dword %0, %1, off" :: "v"(hp), "v"(hw) : "memory");
                } else {
                    asm volatile("global_store_dword %0, %1, off sc0 sc1" :: "v"(sp), "v"(sv) : "memory");
                    asm volatile("global_store_dword %0, %1, off sc0 sc1" :: "v"(hp), "v"(hw) : "memory");
                }
            }

            // all waves: prefetch x-part of t+1 (hides x latency + store flight)
            acc[0] = zero; acc[1] = zero; acc[2] = zero; acc[3] = zero;
            xpart(acc, x, arow, t + 1, kq, bf);

            if (tid < 64) {   // wave 0: compact spin over the whole 8-row slice
                const unsigned short* pb = hbuf + (t & 3) * (BB * HH) + pslice;
                for (;;) {
                    u32x4 pa[8];
                    #pragma unroll
                    for (int i = 0; i < 8; ++i) {
                        if (LOCAL)
                            asm volatile("global_load_dwordx4 %0, %1, off offset:%2 sc0"
                                         : "=&v"(pa[i]) : "v"(pb), "i"(i * 16));
                        else
                            asm volatile("global_load_dwordx4 %0, %1, off offset:%2 sc0 sc1"
                                         : "=&v"(pa[i]) : "v"(pb), "i"(i * 16));
                    }
                    asm volatile("s_waitcnt vmcnt(0)" ::: "memory");
                    unsigned bad = 0u;
                    #pragma unroll
                    for (int i = 0; i < 8; ++i) {
                        bad |= (pa[i][0] == SENT) ? 1u : 0u;
                        bad |= (pa[i][1] == SENT) ? 1u : 0u;
                        bad |= (pa[i][2] == SENT) ? 1u : 0u;
                        bad |= (pa[i][3] == SENT) ? 1u : 0u;
                    }
                    if (__all(bad == 0u)) break;
                    __builtin_amdgcn_s_sleep(1);
                }
                // deferred y store (HBM, fire-and-forget; drains harmlessly later)
                *(f32x2*)&out[((size_t)ebrow * TT + t) * OUTD + ecol0] = hv;
            }
            __syncthreads();
            __builtin_amdgcn_sched_barrier(0);
        }
    }
}

__global__ __launch_bounds__(256, 1) void lstm_rec(
    const float* __restrict__ x, const float* __restrict__ h0, const float* __restrict__ c0,
    const float* __restrict__ wl, const float* __restrict__ bl,
    float* __restrict__ out, unsigned* __restrict__ xccArr, unsigned short* __restrict__ hbuf)
{
    const int bid = blockIdx.x;
    const int tid = threadIdx.x;
    const int w   = tid >> 6;
    const int nl  = tid & 15;
    const int kq  = (tid & 63) >> 4;
    const int bg  = bid & 7;           // batch group (8 rows)
    const int cg  = bid >> 3;          // col group (16 h-cols)

    __shared__ float gates[4][16][17];
    __shared__ int vals[NWG];
    __shared__ int okS;

    // ---- placement discovery: publish XCC via MALL-sentinel (no atomics) ----
    unsigned xcc;
    asm volatile("s_getreg_b32 %0, hwreg(20, 0, 4)" : "=s"(xcc));   // HW_REG_XCC_ID
    if (tid == 0) {
        okS = 1;
        unsigned pv = (xcc & 15u) + 1u;            // nonzero publication
        unsigned* p = xccArr + bid;
        asm volatile("global_store_dword %0, %1, off sc0 sc1" :: "v"(p), "v"(pv) : "memory");
    }
    {   // each thread polls one WG's entry (all 256 WGs co-resident: 1 WG/CU)
        unsigned v;
        unsigned* p = xccArr + tid;
        for (;;) {
            asm volatile("global_load_dword %0, %1, off sc0 sc1" : "=&v"(v) : "v"(p));
            asm volatile("s_waitcnt vmcnt(0)" ::: "memory");
            if (v != 0u) break;
            __builtin_amdgcn_s_sleep(8);
        }
        vals[tid] = (int)(v - 1u);
    }
    __syncthreads();
    if (vals[tid] != vals[tid & 7]) atomicAnd(&okS, 0);   // group must be XCD-uniform
    if (tid < 8) {                                        // 8 groups on 8 distinct XCDs
        #pragma unroll
        for (int j = 0; j < 8; ++j)
            if (j != tid && vals[j] == vals[tid]) atomicAnd(&okS, 0);
    }
    __syncthreads();
    const bool fast = (okS != 0);

    // ---- weight slice -> registers (24 x short8 per lane) ----
    short8 bf[24];
    {
        const int gcol = w * HH + cg * 16 + nl;
        #pragma unroll
        for (int kk = 0; kk < 24; ++kk) {
            short8 v;
            #pragma unroll
            for (int j = 0; j < 8; ++j)
                v[j] = f2bf(wl[(size_t)(kk * 32 + kq * 8 + j) * 2048 + gcol]);
            bf[kk] = v;
        }
    }
    const float bias = bl[w * HH + cg * 16 + nl];

    if (fast) lstm_loop<true >(x, h0, c0, out, hbuf, bf, bias, bg, cg, gates);
    else      lstm_loop<false>(x, h0, c0, out, hbuf, bf, bias, bg, cg, gates);
}

// ---------------------------------------------------------------------------
// w_lin -> Bt (bf16, transposed [n][k]) so B-fragments are contiguous 16B.
// ---------------------------------------------------------------------------
__global__ void conv_wlin(const float* __restrict__ wlin, unsigned short* __restrict__ Bt)
{
    const int g  = blockIdx.x * 256 + threadIdx.x;
    const int n  = g >> 6;
    const int kb = (g & 63) * 8;
    short8 v;
    #pragma unroll
    for (int j = 0; j < 8; ++j) v[j] = f2bf(wlin[(size_t)(kb + j) * OUTD + n]);
    *(short8*)(Bt + (size_t)n * OUTD + kb) = v;
}

// ---------------------------------------------------------------------------
// In-place y = h_hist @ w_lin + b_lin on d_out (32 rows per WG, row-local).
// ---------------------------------------------------------------------------
__global__ __launch_bounds__(256, 2) void out_linear(
    float* __restrict__ out, const unsigned short* __restrict__ Bt, const float* __restrict__ blin)
{
    const int r0  = blockIdx.x * 32;
    const int tid = threadIdx.x;
    const int w = tid >> 6, lane = tid & 63, nl = lane & 15, kq = lane >> 4;

    __shared__ unsigned short aLds[32][520];

    {   // stage 32 rows x 512 fp32 -> bf16 LDS
        const int row = tid >> 3;
        const int cb  = (tid & 7) * 64;
        const float* src = out + (size_t)(r0 + row) * OUTD + cb;
        #pragma unroll
        for (int c = 0; c < 64; c += 4) {
            f32x4 v = *(const f32x4*)(src + c);
            aLds[row][cb + c + 0] = (unsigned short)f2bf(v[0]);
            aLds[row][cb + c + 1] = (unsigned short)f2bf(v[1]);
            aLds[row][cb + c + 2] = (unsigned short)f2bf(v[2]);
            aLds[row][cb + c + 3] = (unsigned short)f2bf(v[3]);
        }
    }
    __syncthreads();

    const f32x4 zero = {0.f, 0.f, 0.f, 0.f};
    f32x4 acc[2][8];
    #pragma unroll
    for (int m = 0; m < 2; ++m)
        #pragma unroll
        for (int n = 0; n < 8; ++n) acc[m][n] = zero;

    #pragma unroll
    for (int kk = 0; kk < 16; ++kk) {
        short8 A0 = *(const short8*)&aLds[nl][kk * 32 + kq * 8];
        short8 A1 = *(const short8*)&aLds[16 + nl][kk * 32 + kq * 8];
        #pragma unroll
        for (int n = 0; n < 8; ++n) {
            const int nt = w * 8 + n;
            short8 Bv = *(const short8*)(Bt + (size_t)(nt * 16 + nl) * OUTD + kk * 32 + kq * 8);
            acc[0][n] = MFMA(A0, Bv, acc[0][n]);
            acc[1][n] = MFMA(A1, Bv, acc[1][n]);
        }
    }

    #pragma unroll
    for (int mt = 0; mt < 2; ++mt)
        #pragma unroll
        for (int n = 0; n < 8; ++n) {
            const int col = (w * 8 + n) * 16 + nl;
            const float bb = blin[col];
            #pragma unroll
            for (int r = 0; r < 4; ++r)
                out[(size_t)(r0 + mt * 16 + kq * 4 + r) * OUTD + col] = acc[mt][n][r] + bb;
        }
}

// ---------------------------------------------------------------------------
extern "C" void kernel_launch(void* const* d_in, const int* in_sizes, int n_in,
                              void* d_out, int out_size, void* d_ws, size_t ws_size,
                              hipStream_t stream)
{
    const float* x    = (const float*)d_in[0];
    const float* h0   = (const float*)d_in[1];
    const float* c0   = (const float*)d_in[2];
    const float* wl   = (const float*)d_in[3];
    const float* bl   = (const float*)d_in[4];
    const float* wlin = (const float*)d_in[5];
    const float* blin = (const float*)d_in[6];
    float* out = (float*)d_out;

    unsigned*       xccArr = (unsigned*)d_ws;                                   // 1KB used
    unsigned short* hbuf   = (unsigned short*)((char*)d_ws + 4096);             // 4 x 64KB h buffers
    unsigned short* Bt     = (unsigned short*)((char*)d_ws + 4096 + 4 * BB * HH * 2);

    hipMemsetAsync(d_ws, 0, 4096, stream);                 // zero xccArr
    hipMemsetAsync(hbuf, 0x7F, 4 * BB * HH * 2, stream);   // pre-fill sentinel
    conv_wlin<<<128, 256, 0, stream>>>(wlin, Bt);
    lstm_rec<<<NWG, 256, 0, stream>>>(x, h0, c0, wl, bl, out, xccArr, hbuf);
    out_linear<<<(BB * TT) / 32, 256, 0, stream>>>(out, Bt, blin);
}

// Round 8
// 3598.131 us; speedup vs baseline: 1.7499x; 1.7499x over previous
//
#include <hip/hip_runtime.h>

// LSTM: B=64, T=1024, IN=256, H=512, gates=2048; then Linear 512->512.
// Inputs (fp32): x, h0, c0, w_lstm[768,2048], b_lstm[2048], w_lin[512,512], b_lin[512]
// Output (fp32): y[64,1024,512] ++ h_fin[64,512] ++ c_fin[64,512]
//
// 256 WGs (1/CU): 8 batch-groups (8 rows, bg=bid&7) x 32 col-groups (16 h-cols).
// Sentinel sync (data IS the flag; 0x7F7F unreachable since |h|<1). Fast path:
// XCD-local L2 (runtime-verified placement); fallback: MALL (sc0 sc1).
// R8: cheap 32-dword probe (wave0) -> raw barrier -> cooperative 8KB fill of h
// into LDS (sc0, verify-from-regs + retry) -> all waves MFMA from LDS.
// x(t+1) issued as C-level loads after the B-barrier: latency crosses the raw
// A2 barrier and drains in the fill's vmcnt(0) (off the critical chain).

#define BB   64
#define TT   1024
#define DIN  256
#define HH   512
#define OUTD 512
#define NWG  256
#define YTOT (BB*TT*OUTD)
#define SENT 0x7F7F7F7Fu
#define HROW 520   // padded LDS row stride (elements): 1040B -> +4 bank shift/row

typedef __attribute__((ext_vector_type(4))) float f32x4;
typedef __attribute__((ext_vector_type(2))) float f32x2;
typedef __attribute__((ext_vector_type(4))) unsigned u32x4;
typedef __attribute__((ext_vector_type(8))) short short8;

__device__ inline short f2bf(float f) {
    unsigned u = __float_as_uint(f);
    unsigned r = u + 0x7fffu + ((u >> 16) & 1u);   // RNE
    return (short)(r >> 16);
}
__device__ inline float sigf(float x) { return 1.0f / (1.0f + __expf(-x)); }
__device__ inline float tanhfast(float x) { return 1.0f - 2.0f / (__expf(2.0f * x) + 1.0f); }

__device__ inline short8 pack8(f32x4 lo, f32x4 hi) {
    short8 a;
    a[0] = f2bf(lo[0]); a[1] = f2bf(lo[1]); a[2] = f2bf(lo[2]); a[3] = f2bf(lo[3]);
    a[4] = f2bf(hi[0]); a[5] = f2bf(hi[1]); a[6] = f2bf(hi[2]); a[7] = f2bf(hi[3]);
    return a;
}

#define MFMA(a, b, c) __builtin_amdgcn_mfma_f32_16x16x32_bf16((a), (b), (c), 0, 0, 0)

template<bool LOCAL>
__device__ inline void lstm_loop(const float* __restrict__ x, const float* __restrict__ h0,
                                 const float* __restrict__ c0, float* __restrict__ out,
                                 unsigned short* __restrict__ hbuf,
                                 const short8* bf, float bias, int bg, int cg,
                                 float (*gates)[16][17], unsigned short* hlds, int* shBad)
{
    const int tid  = threadIdx.x;
    const int w    = tid >> 6;
    const int lane = tid & 63;
    const int nl   = lane & 15;
    const int kq   = lane >> 4;

    // Elementwise mapping: wave 0 (tid<64) owns (row 0..7, col-pair 0..7).
    const bool ew   = (tid < 64);
    const int ebl   = (tid >> 3) & 7;
    const int ej2   = tid & 7;
    const int ebrow = bg * 8 + ebl;
    const int ecol0 = cg * 16 + ej2 * 2;
    f32x2 creg = {0.f, 0.f};
    if (ew) creg = *(const f32x2*)&c0[(size_t)ebrow * HH + ecol0];

    const int arow = bg * 8 + (nl & 7);    // A rows 8..15 duplicate 0..7
    const size_t sliceBase = (size_t)(bg * 8) * HH;

    const f32x4 zero = {0.f, 0.f, 0.f, 0.f};
    f32x4 xlo[8], xhi[8];
    short8 xr[8];

    for (int t = 0; t < TT; ++t) {
        f32x4 acc[4] = {zero, zero, zero, zero};

        if (t == 0) {
            // ---- direct path for t=0: x(0) + h0 from global (read-only inputs)
            const float* xp = x + (size_t)arow * TT * DIN + kq * 8;
            #pragma unroll
            for (int k = 0; k < 8; ++k) {
                f32x4 lo = *(const f32x4*)(xp + k * 32);
                f32x4 hi = *(const f32x4*)(xp + k * 32 + 4);
                acc[k & 3] = MFMA(pack8(lo, hi), bf[k], acc[k & 3]);
            }
            const float* hp = h0 + (size_t)arow * HH + kq * 8;
            #pragma unroll
            for (int kk = 0; kk < 16; ++kk) {
                f32x4 lo = *(const f32x4*)(hp + kk * 32);
                f32x4 hi = *(const f32x4*)(hp + kk * 32 + 4);
                acc[kk & 3] = MFMA(pack8(lo, hi), bf[8 + kk], acc[kk & 3]);
            }
        } else {
            const size_t bufO = (size_t)((t - 1) & 3) * (BB * HH);

            // ---- A1: wave0 probes one dword per producer WG (32 dwords)
            if (tid < 64) {
                const unsigned short* pb = hbuf + bufO + sliceBase + (size_t)(lane & 31) * 16;
                for (;;) {
                    unsigned pv;
                    if (LOCAL)
                        asm volatile("global_load_dword %0, %1, off sc0" : "=&v"(pv) : "v"(pb));
                    else
                        asm volatile("global_load_dword %0, %1, off sc0 sc1" : "=&v"(pv) : "v"(pb));
                    asm volatile("s_waitcnt vmcnt(0)" ::: "memory");
                    if (__all(pv != SENT)) break;
                    __builtin_amdgcn_s_sleep(1);
                }
            }
            // ---- A2: raw barrier (no vmcnt drain: waves 1-3 carry x loads across)
            __builtin_amdgcn_s_barrier();
            __builtin_amdgcn_sched_barrier(0);

            // ---- A3/A4: cooperative fill 8KB h-slice -> LDS, verify, retry
            {
                const unsigned short* gp = hbuf + bufO + sliceBase
                                         + (size_t)(tid >> 5) * HH + (size_t)(tid & 31) * 16;
                unsigned short* lp = hlds + (tid >> 5) * HROW + (tid & 31) * 16;
                for (;;) {
                    u32x4 a0, a1;
                    if (LOCAL) {
                        asm volatile("global_load_dwordx4 %0, %1, off sc0" : "=&v"(a0) : "v"(gp));
                        asm volatile("global_load_dwordx4 %0, %1, off offset:16 sc0" : "=&v"(a1) : "v"(gp));
                    } else {
                        asm volatile("global_load_dwordx4 %0, %1, off sc0 sc1" : "=&v"(a0) : "v"(gp));
                        asm volatile("global_load_dwordx4 %0, %1, off offset:16 sc0 sc1" : "=&v"(a1) : "v"(gp));
                    }
                    asm volatile("s_waitcnt vmcnt(0)" ::: "memory");
                    __builtin_amdgcn_sched_barrier(0);
                    int bad = (a0[0] == SENT) | (a0[1] == SENT) | (a0[2] == SENT) | (a0[3] == SENT)
                            | (a1[0] == SENT) | (a1[1] == SENT) | (a1[2] == SENT) | (a1[3] == SENT);
                    if (bad) atomicOr(shBad, 1);
                    *(u32x4*)lp = a0;
                    *(u32x4*)(lp + 8) = a1;
                    __syncthreads();
                    int b = *shBad;
                    if (!b) break;          // uniform
                    __syncthreads();
                    if (tid == 0) *shBad = 0;
                    __syncthreads();
                }
            }

            // ---- pack x(t) (loaded at D of step t-1; drained by fill vmcnt(0))
            #pragma unroll
            for (int k = 0; k < 8; ++k) xr[k] = pack8(xlo[k], xhi[k]);

            // ---- A6: MFMA — x from regs, h from LDS
            #pragma unroll
            for (int k = 0; k < 8; ++k)
                acc[k & 3] = MFMA(xr[k], bf[k], acc[k & 3]);
            const unsigned short* hr = hlds + (nl & 7) * HROW + kq * 8;
            #pragma unroll
            for (int kk = 0; kk < 16; ++kk) {
                short8 ha = *(const short8*)(hr + kk * 32);
                acc[kk & 3] = MFMA(ha, bf[8 + kk], acc[kk & 3]);
            }
        }

        // ---- B: gate tile -> LDS (C layout: row=kq*4+r, col=nl; rows 8-15 dup)
        #pragma unroll
        for (int r = 0; r < 4; ++r)
            gates[w][kq * 4 + r][nl] = acc[0][r] + acc[1][r] + acc[2][r] + acc[3][r] + bias;
        __syncthreads();

        if (t < TT - 1) {
            // ---- D: issue x(t+1) loads (C-level; fly across the raw A2 barrier)
            {
                const float* xp = x + ((size_t)arow * TT + (t + 1)) * DIN + kq * 8;
                #pragma unroll
                for (int k = 0; k < 8; ++k) {
                    xlo[k] = *(const f32x4*)(xp + k * 32);
                    xhi[k] = *(const f32x4*)(xp + k * 32 + 4);
                }
            }
            // ---- C: elementwise + publish (wave 0)
            if (ew) {
                float i0 = gates[0][ebl][ej2 * 2], i1 = gates[0][ebl][ej2 * 2 + 1];
                float g0 = gates[1][ebl][ej2 * 2], g1 = gates[1][ebl][ej2 * 2 + 1];
                float f0 = gates[2][ebl][ej2 * 2], f1 = gates[2][ebl][ej2 * 2 + 1];
                float o0 = gates[3][ebl][ej2 * 2], o1 = gates[3][ebl][ej2 * 2 + 1];
                creg[0] = sigf(f0 + 1.0f) * creg[0] + sigf(i0) * tanhfast(g0);
                creg[1] = sigf(f1 + 1.0f) * creg[1] + sigf(i1) * tanhfast(g1);
                float hn0 = sigf(o0) * tanhfast(creg[0]);
                float hn1 = sigf(o1) * tanhfast(creg[1]);

                unsigned hw = (unsigned)(unsigned short)f2bf(hn0)
                            | ((unsigned)(unsigned short)f2bf(hn1) << 16);
                const size_t slot = (size_t)ebrow * HH + ecol0;
                unsigned short* hp = hbuf + (size_t)(t & 3) * (BB * HH) + slot;
                unsigned short* sp = hbuf + (size_t)((t + 2) & 3) * (BB * HH) + slot;
                unsigned sv = SENT;
                // sentinel-reset (buf reused at t+2) then h publish. Both are
                // drained by this wave's next probe vmcnt(0) before h(t+1) is
                // published -> reset(t+2) globally visible before anyone can
                // poll buf[t+2] (they must consume t+1 first).
                if (LOCAL) {
                    asm volatile("global_store_dword %0, %1, off" :: "v"(sp), "v"(sv) : "memory");
                    asm volatile("global_store_dword %0, %1, off" :: "v"(hp), "v"(hw) : "memory");
                } else {
                    asm volatile("global_store_dword %0, %1, off sc0 sc1" :: "v"(sp), "v"(sv) : "memory");
                    asm volatile("global_store_dword %0, %1, off sc0 sc1" :: "v"(hp), "v"(hw) : "memory");
                }
                f32x2 hv = {hn0, hn1};
                *(f32x2*)&out[((size_t)ebrow * TT + t) * OUTD + ecol0] = hv;
            }
        } else {
            if (ew) {
                float i0 = gates[0][ebl][ej2 * 2], i1 = gates[0][ebl][ej2 * 2 + 1];
                float g0 = gates[1][ebl][ej2 * 2], g1 = gates[1][ebl][ej2 * 2 + 1];
                float f0 = gates[2][ebl][ej2 * 2], f1 = gates[2][ebl][ej2 * 2 + 1];
                float o0 = gates[3][ebl][ej2 * 2], o1 = gates[3][ebl][ej2 * 2 + 1];
                creg[0] = sigf(f0 + 1.0f) * creg[0] + sigf(i0) * tanhfast(g0);
                creg[1] = sigf(f1 + 1.0f) * creg[1] + sigf(i1) * tanhfast(g1);
                f32x2 hv = { sigf(o0) * tanhfast(creg[0]), sigf(o1) * tanhfast(creg[1]) };
                *(f32x2*)&out[((size_t)ebrow * TT + t) * OUTD + ecol0] = hv;
                *(f32x2*)&out[YTOT + (size_t)ebrow * OUTD + ecol0] = hv;               // h_fin
                *(f32x2*)&out[YTOT + BB * OUTD + (size_t)ebrow * OUTD + ecol0] = creg; // c_fin
            }
        }
    }
}

__global__ __launch_bounds__(256, 1) void lstm_rec(
    const float* __restrict__ x, const float* __restrict__ h0, const float* __restrict__ c0,
    const float* __restrict__ wl, const float* __restrict__ bl,
    float* __restrict__ out, unsigned* __restrict__ xccArr, unsigned short* __restrict__ hbuf)
{
    const int bid = blockIdx.x;
    const int tid = threadIdx.x;
    const int w   = tid >> 6;
    const int nl  = tid & 15;
    const int kq  = (tid & 63) >> 4;
    const int bg  = bid & 7;           // batch group (8 rows)
    const int cg  = bid >> 3;          // col group (16 h-cols)

    __shared__ float gates[4][16][17];
    __shared__ unsigned short hlds[8 * HROW];   // padded 8-row h tile (8320B)
    __shared__ int shBad;
    __shared__ int vals[NWG];
    __shared__ int okS;

    // ---- placement discovery: publish XCC via MALL-sentinel (no atomics) ----
    unsigned xcc;
    asm volatile("s_getreg_b32 %0, hwreg(20, 0, 4)" : "=s"(xcc));   // HW_REG_XCC_ID
    if (tid == 0) {
        okS = 1; shBad = 0;
        unsigned pv = (xcc & 15u) + 1u;            // nonzero publication
        unsigned* p = xccArr + bid;
        asm volatile("global_store_dword %0, %1, off sc0 sc1" :: "v"(p), "v"(pv) : "memory");
    }
    {   // each thread polls one WG's entry (all 256 WGs co-resident: 1 WG/CU)
        unsigned v;
        unsigned* p = xccArr + tid;
        for (;;) {
            asm volatile("global_load_dword %0, %1, off sc0 sc1" : "=&v"(v) : "v"(p));
            asm volatile("s_waitcnt vmcnt(0)" ::: "memory");
            if (v != 0u) break;
            __builtin_amdgcn_s_sleep(8);
        }
        vals[tid] = (int)(v - 1u);
    }
    __syncthreads();
    if (vals[tid] != vals[tid & 7]) atomicAnd(&okS, 0);   // group must be XCD-uniform
    if (tid < 8) {                                        // 8 groups on 8 distinct XCDs
        #pragma unroll
        for (int j = 0; j < 8; ++j)
            if (j != tid && vals[j] == vals[tid]) atomicAnd(&okS, 0);
    }
    __syncthreads();
    const bool fast = (okS != 0);

    // ---- weight slice -> registers (24 x short8 per lane) ----
    short8 bf[24];
    {
        const int gcol = w * HH + cg * 16 + nl;
        #pragma unroll
        for (int kk = 0; kk < 24; ++kk) {
            short8 v;
            #pragma unroll
            for (int j = 0; j < 8; ++j)
                v[j] = f2bf(wl[(size_t)(kk * 32 + kq * 8 + j) * 2048 + gcol]);
            bf[kk] = v;
        }
    }
    const float bias = bl[w * HH + cg * 16 + nl];

    if (fast) lstm_loop<true >(x, h0, c0, out, hbuf, bf, bias, bg, cg, gates, hlds, &shBad);
    else      lstm_loop<false>(x, h0, c0, out, hbuf, bf, bias, bg, cg, gates, hlds, &shBad);
}

// ---------------------------------------------------------------------------
// w_lin -> Bt (bf16, transposed [n][k]) so B-fragments are contiguous 16B.
// ---------------------------------------------------------------------------
__global__ void conv_wlin(const float* __restrict__ wlin, unsigned short* __restrict__ Bt)
{
    const int g  = blockIdx.x * 256 + threadIdx.x;
    const int n  = g >> 6;
    const int kb = (g & 63) * 8;
    short8 v;
    #pragma unroll
    for (int j = 0; j < 8; ++j) v[j] = f2bf(wlin[(size_t)(kb + j) * OUTD + n]);
    *(short8*)(Bt + (size_t)n * OUTD + kb) = v;
}

// ---------------------------------------------------------------------------
// In-place y = h_hist @ w_lin + b_lin on d_out (32 rows per WG, row-local).
// ---------------------------------------------------------------------------
__global__ __launch_bounds__(256, 2) void out_linear(
    float* __restrict__ out, const unsigned short* __restrict__ Bt, const float* __restrict__ blin)
{
    const int r0  = blockIdx.x * 32;
    const int tid = threadIdx.x;
    const int w = tid >> 6, lane = tid & 63, nl = lane & 15, kq = lane >> 4;

    __shared__ unsigned short aLds[32][520];

    {   // stage 32 rows x 512 fp32 -> bf16 LDS
        const int row = tid >> 3;
        const int cb  = (tid & 7) * 64;
        const float* src = out + (size_t)(r0 + row) * OUTD + cb;
        #pragma unroll
        for (int c = 0; c < 64; c += 4) {
            f32x4 v = *(const f32x4*)(src + c);
            aLds[row][cb + c + 0] = (unsigned short)f2bf(v[0]);
            aLds[row][cb + c + 1] = (unsigned short)f2bf(v[1]);
            aLds[row][cb + c + 2] = (unsigned short)f2bf(v[2]);
            aLds[row][cb + c + 3] = (unsigned short)f2bf(v[3]);
        }
    }
    __syncthreads();

    const f32x4 zero = {0.f, 0.f, 0.f, 0.f};
    f32x4 acc[2][8];
    #pragma unroll
    for (int m = 0; m < 2; ++m)
        #pragma unroll
        for (int n = 0; n < 8; ++n) acc[m][n] = zero;

    #pragma unroll
    for (int kk = 0; kk < 16; ++kk) {
        short8 A0 = *(const short8*)&aLds[nl][kk * 32 + kq * 8];
        short8 A1 = *(const short8*)&aLds[16 + nl][kk * 32 + kq * 8];
        #pragma unroll
        for (int n = 0; n < 8; ++n) {
            const int nt = w * 8 + n;
            short8 Bv = *(const short8*)(Bt + (size_t)(nt * 16 + nl) * OUTD + kk * 32 + kq * 8);
            acc[0][n] = MFMA(A0, Bv, acc[0][n]);
            acc[1][n] = MFMA(A1, Bv, acc[1][n]);
        }
    }

    #pragma unroll
    for (int mt = 0; mt < 2; ++mt)
        #pragma unroll
        for (int n = 0; n < 8; ++n) {
            const int col = (w * 8 + n) * 16 + nl;
            const float bb = blin[col];
            #pragma unroll
            for (int r = 0; r < 4; ++r)
                out[(size_t)(r0 + mt * 16 + kq * 4 + r) * OUTD + col] = acc[mt][n][r] + bb;
        }
}

// ---------------------------------------------------------------------------
extern "C" void kernel_launch(void* const* d_in, const int* in_sizes, int n_in,
                              void* d_out, int out_size, void* d_ws, size_t ws_size,
                              hipStream_t stream)
{
    const float* x    = (const float*)d_in[0];
    const float* h0   = (const float*)d_in[1];
    const float* c0   = (const float*)d_in[2];
    const float* wl   = (const float*)d_in[3];
    const float* bl   = (const float*)d_in[4];
    const float* wlin = (const float*)d_in[5];
    const float* blin = (const float*)d_in[6];
    float* out = (float*)d_out;

    unsigned*       xccArr = (unsigned*)d_ws;                                   // 1KB used
    unsigned short* hbuf   = (unsigned short*)((char*)d_ws + 4096);             // 4 x 64KB h buffers
    unsigned short* Bt     = (unsigned short*)((char*)d_ws + 4096 + 4 * BB * HH * 2);

    hipMemsetAsync(d_ws, 0, 4096, stream);                 // zero xccArr
    hipMemsetAsync(hbuf, 0x7F, 4 * BB * HH * 2, stream);   // pre-fill sentinel
    conv_wlin<<<128, 256, 0, stream>>>(wlin, Bt);
    lstm_rec<<<NWG, 256, 0, stream>>>(x, h0, c0, wl, bl, out, xccArr, hbuf);
    out_linear<<<(BB * TT) / 32, 256, 0, stream>>>(out, Bt, blin);
}

// Round 14
// 2287.975 us; speedup vs baseline: 2.7519x; 1.5726x over previous
//
#include <hip/hip_runtime.h>

// LSTM: B=64, T=1024, IN=256, H=512, gates=2048; then Linear 512->512.
// Inputs (fp32): x, h0, c0, w_lstm[768,2048], b_lstm[2048], w_lin[512,512], b_lin[512]
// Output (fp32): y[64,1024,512] ++ h_fin[64,512] ++ c_fin[64,512]
//
// 256 WGs (1/CU): 8 batch-groups (8 rows, bg=bid&7) x 32 col-groups (16 h-cols).
// Sentinel sync (data IS the flag; 0x7F7F unreachable since |h|<1). Fast path:
// XCD-local L2 (runtime-verified placement); fallback: MALL (sc0 sc1).
// R14 = R8 EXACTLY (passed validation+timing+revalidation @3.71ms) + PREX only:
//   x pre-converted to bf16 t-major (conv_x, validated in R13 launch 1);
//   C-level short8 prefetch; per-step pack8 (~640cy serial VALU) deleted.
// R12/R13's loop caps + placement bail are REMOVED: the bounded placement poll
// could make WGs DISAGREE on fast-vs-MALL (split-protocol -> wedge -> silent
// garbage during replays = R13's re-validation failure). R8's unbounded polls
// guarantee all WGs see identical data -> identical protocol choice.

#define BB   64
#define TT   1024
#define DIN  256
#define HH   512
#define OUTD 512
#define NWG  256
#define YTOT (BB*TT*OUTD)
#define SENT 0x7F7F7F7Fu
#define HROW 520   // padded LDS row stride (elements)

typedef __attribute__((ext_vector_type(4))) float f32x4;
typedef __attribute__((ext_vector_type(2))) float f32x2;
typedef __attribute__((ext_vector_type(4))) unsigned u32x4;
typedef __attribute__((ext_vector_type(8))) short short8;

__device__ inline short f2bf(float f) {
    unsigned u = __float_as_uint(f);
    unsigned r = u + 0x7fffu + ((u >> 16) & 1u);   // RNE
    return (short)(r >> 16);
}
__device__ inline float sigf(float x) { return 1.0f / (1.0f + __expf(-x)); }
__device__ inline float tanhfast(float x) { return 1.0f - 2.0f / (__expf(2.0f * x) + 1.0f); }

__device__ inline short8 pack8(f32x4 lo, f32x4 hi) {
    short8 a;
    a[0] = f2bf(lo[0]); a[1] = f2bf(lo[1]); a[2] = f2bf(lo[2]); a[3] = f2bf(lo[3]);
    a[4] = f2bf(hi[0]); a[5] = f2bf(hi[1]); a[6] = f2bf(hi[2]); a[7] = f2bf(hi[3]);
    return a;
}

#define MFMA(a, b, c) __builtin_amdgcn_mfma_f32_16x16x32_bf16((a), (b), (c), 0, 0, 0)

template<bool LOCAL, bool PREX>
__device__ inline void lstm_loop(const float* __restrict__ x, const unsigned short* __restrict__ xs,
                                 const float* __restrict__ h0, const float* __restrict__ c0,
                                 float* __restrict__ out, unsigned short* __restrict__ hbuf,
                                 const short8* bf, float bias, int bg, int cg,
                                 float (*gates)[16][17], unsigned short* hlds, int* shBad)
{
    const int tid  = threadIdx.x;
    const int w    = tid >> 6;
    const int lane = tid & 63;
    const int nl   = lane & 15;
    const int kq   = lane >> 4;

    const bool ew   = (tid < 64);
    const int ebl   = (tid >> 3) & 7;
    const int ej2   = tid & 7;
    const int ebrow = bg * 8 + ebl;
    const int ecol0 = cg * 16 + ej2 * 2;
    f32x2 creg = {0.f, 0.f};
    if (ew) creg = *(const f32x2*)&c0[(size_t)ebrow * HH + ecol0];

    const int arow = bg * 8 + (nl & 7);
    const size_t sliceBase = (size_t)(bg * 8) * HH;

    const f32x4 zero = {0.f, 0.f, 0.f, 0.f};
    short8 xv[8];              // PREX: x(t) fragments (prefetched, C-level)
    f32x4 xlo[8], xhi[8];      // !PREX: fp32 x prefetch (R8 path)

    for (int t = 0; t < TT; ++t) {
        f32x4 acc[4] = {zero, zero, zero, zero};

        if (t == 0) {
            // ---- direct path for t=0: x(0) + h0 (read-only inputs)
            if (PREX) {
                const unsigned short* xp = xs + (size_t)arow * DIN + kq * 8;
                #pragma unroll
                for (int k = 0; k < 8; ++k) xv[k] = *(const short8*)(xp + k * 32);
            } else {
                const float* xp = x + (size_t)arow * TT * DIN + kq * 8;
                #pragma unroll
                for (int k = 0; k < 8; ++k)
                    xv[k] = pack8(*(const f32x4*)(xp + k * 32), *(const f32x4*)(xp + k * 32 + 4));
            }
            #pragma unroll
            for (int k = 0; k < 8; ++k)
                acc[k & 3] = MFMA(xv[k], bf[k], acc[k & 3]);
            const float* hp = h0 + (size_t)arow * HH + kq * 8;
            #pragma unroll
            for (int kk = 0; kk < 16; ++kk) {
                f32x4 lo = *(const f32x4*)(hp + kk * 32);
                f32x4 hi = *(const f32x4*)(hp + kk * 32 + 4);
                acc[kk & 3] = MFMA(pack8(lo, hi), bf[8 + kk], acc[kk & 3]);
            }
        } else {
            const size_t bufO = (size_t)((t - 1) & 3) * (BB * HH);

            // ---- A1: wave0 probes one dword per producer WG (R8 exact)
            if (tid < 64) {
                const unsigned short* pb = hbuf + bufO + sliceBase + (size_t)(lane & 31) * 16;
                unsigned pv;
                for (;;) {
                    if (LOCAL)
                        asm volatile("global_load_dword %0, %1, off sc0" : "=&v"(pv) : "v"(pb));
                    else
                        asm volatile("global_load_dword %0, %1, off sc0 sc1" : "=&v"(pv) : "v"(pb));
                    asm volatile("s_waitcnt vmcnt(0)" ::: "memory");
                    if (__all(pv != SENT)) break;
                    __builtin_amdgcn_s_sleep(1);
                }
            }
            // ---- A2: raw barrier (waves 1-3 carry x prefetch across unharmed)
            __builtin_amdgcn_s_barrier();
            __builtin_amdgcn_sched_barrier(0);

            // ---- A3/A4: cooperative fill 8KB h-slice -> LDS, verify, retry
            {
                const unsigned short* gp = hbuf + bufO + sliceBase
                                         + (size_t)(tid >> 5) * HH + (size_t)(tid & 31) * 16;
                unsigned short* lp = hlds + (tid >> 5) * HROW + (tid & 31) * 16;
                for (;;) {
                    u32x4 a0, a1;
                    if (LOCAL) {
                        asm volatile("global_load_dwordx4 %0, %1, off sc0" : "=&v"(a0) : "v"(gp));
                        asm volatile("global_load_dwordx4 %0, %1, off offset:16 sc0" : "=&v"(a1) : "v"(gp));
                    } else {
                        asm volatile("global_load_dwordx4 %0, %1, off sc0 sc1" : "=&v"(a0) : "v"(gp));
                        asm volatile("global_load_dwordx4 %0, %1, off offset:16 sc0 sc1" : "=&v"(a1) : "v"(gp));
                    }
                    asm volatile("s_waitcnt vmcnt(0)" ::: "memory");
                    __builtin_amdgcn_sched_barrier(0);
                    int bad = (a0[0] == SENT) | (a0[1] == SENT) | (a0[2] == SENT) | (a0[3] == SENT)
                            | (a1[0] == SENT) | (a1[1] == SENT) | (a1[2] == SENT) | (a1[3] == SENT);
                    if (bad) atomicOr(shBad, 1);
                    *(u32x4*)lp = a0;
                    *(u32x4*)(lp + 8) = a1;
                    __syncthreads();
                    int b = *shBad;
                    if (!b) break;          // uniform
                    __syncthreads();
                    if (tid == 0) *shBad = 0;
                    __syncthreads();
                }
            }

            // ---- x(t): PREX -> already bf16 in xv (issued at D of t-1, drained
            //      by the fill's vmcnt(0)); !PREX -> pack now (R8)
            if (!PREX) {
                #pragma unroll
                for (int k = 0; k < 8; ++k) xv[k] = pack8(xlo[k], xhi[k]);
            }

            // ---- A6: MFMA — x from regs, h from LDS
            #pragma unroll
            for (int k = 0; k < 8; ++k)
                acc[k & 3] = MFMA(xv[k], bf[k], acc[k & 3]);
            const unsigned short* hr = hlds + (nl & 7) * HROW + kq * 8;
            #pragma unroll
            for (int kk = 0; kk < 16; ++kk) {
                short8 ha = *(const short8*)(hr + kk * 32);
                acc[kk & 3] = MFMA(ha, bf[8 + kk], acc[kk & 3]);
            }
        }

        // ---- B: gate tile -> LDS (C layout: row=kq*4+r, col=nl; rows 8-15 dup)
        #pragma unroll
        for (int r = 0; r < 4; ++r)
            gates[w][kq * 4 + r][nl] = acc[0][r] + acc[1][r] + acc[2][r] + acc[3][r] + bias;
        __syncthreads();

        if (t < TT - 1) {
            // ---- D: issue x(t+1) prefetch (C-level; consumed after next fill)
            if (PREX) {
                const unsigned short* xp = xs + ((size_t)(t + 1) * BB + arow) * DIN + kq * 8;
                #pragma unroll
                for (int k = 0; k < 8; ++k) xv[k] = *(const short8*)(xp + k * 32);
            } else {
                const float* xp = x + ((size_t)arow * TT + (t + 1)) * DIN + kq * 8;
                #pragma unroll
                for (int k = 0; k < 8; ++k) {
                    xlo[k] = *(const f32x4*)(xp + k * 32);
                    xhi[k] = *(const f32x4*)(xp + k * 32 + 4);
                }
            }
            // ---- C: elementwise + publish (wave 0)
            if (ew) {
                float i0 = gates[0][ebl][ej2 * 2], i1 = gates[0][ebl][ej2 * 2 + 1];
                float g0 = gates[1][ebl][ej2 * 2], g1 = gates[1][ebl][ej2 * 2 + 1];
                float f0 = gates[2][ebl][ej2 * 2], f1 = gates[2][ebl][ej2 * 2 + 1];
                float o0 = gates[3][ebl][ej2 * 2], o1 = gates[3][ebl][ej2 * 2 + 1];
                creg[0] = sigf(f0 + 1.0f) * creg[0] + sigf(i0) * tanhfast(g0);
                creg[1] = sigf(f1 + 1.0f) * creg[1] + sigf(i1) * tanhfast(g1);
                float hn0 = sigf(o0) * tanhfast(creg[0]);
                float hn1 = sigf(o1) * tanhfast(creg[1]);

                unsigned hw = (unsigned)(unsigned short)f2bf(hn0)
                            | ((unsigned)(unsigned short)f2bf(hn1) << 16);
                const size_t slot = (size_t)ebrow * HH + ecol0;
                unsigned short* hp = hbuf + (size_t)(t & 3) * (BB * HH) + slot;
                unsigned short* sp = hbuf + (size_t)((t + 2) & 3) * (BB * HH) + slot;
                unsigned sv = SENT;
                // reset(t+2) + publish h(t): both drained at this wave's next
                // probe vmcnt(0) before h(t+1) can exist -> no ABA.
                if (LOCAL) {
                    asm volatile("global_store_dword %0, %1, off" :: "v"(sp), "v"(sv) : "memory");
                    asm volatile("global_store_dword %0, %1, off" :: "v"(hp), "v"(hw) : "memory");
                } else {
                    asm volatile("global_store_dword %0, %1, off sc0 sc1" :: "v"(sp), "v"(sv) : "memory");
                    asm volatile("global_store_dword %0, %1, off sc0 sc1" :: "v"(hp), "v"(hw) : "memory");
                }
                f32x2 hv = {hn0, hn1};
                float* yp = &out[((size_t)ebrow * TT + t) * OUTD + ecol0];
                asm volatile("global_store_dwordx2 %0, %1, off" :: "v"(yp), "v"(hv) : "memory");
            }
        } else {
            if (ew) {
                float i0 = gates[0][ebl][ej2 * 2], i1 = gates[0][ebl][ej2 * 2 + 1];
                float g0 = gates[1][ebl][ej2 * 2], g1 = gates[1][ebl][ej2 * 2 + 1];
                float f0 = gates[2][ebl][ej2 * 2], f1 = gates[2][ebl][ej2 * 2 + 1];
                float o0 = gates[3][ebl][ej2 * 2], o1 = gates[3][ebl][ej2 * 2 + 1];
                creg[0] = sigf(f0 + 1.0f) * creg[0] + sigf(i0) * tanhfast(g0);
                creg[1] = sigf(f1 + 1.0f) * creg[1] + sigf(i1) * tanhfast(g1);
                f32x2 hv = { sigf(o0) * tanhfast(creg[0]), sigf(o1) * tanhfast(creg[1]) };
                *(f32x2*)&out[((size_t)ebrow * TT + t) * OUTD + ecol0] = hv;
                *(f32x2*)&out[YTOT + (size_t)ebrow * OUTD + ecol0] = hv;               // h_fin
                *(f32x2*)&out[YTOT + BB * OUTD + (size_t)ebrow * OUTD + ecol0] = creg; // c_fin
            }
        }
    }
}

template<bool PREX>
__global__ __launch_bounds__(256, 1) void lstm_rec(
    const float* __restrict__ x, const unsigned short* __restrict__ xs,
    const float* __restrict__ h0, const float* __restrict__ c0,
    const float* __restrict__ wl, const float* __restrict__ bl,
    float* __restrict__ out, unsigned* __restrict__ xccArr, unsigned short* __restrict__ hbuf)
{
    const int bid = blockIdx.x;
    const int tid = threadIdx.x;
    const int w   = tid >> 6;
    const int nl  = tid & 15;
    const int kq  = (tid & 63) >> 4;
    const int bg  = bid & 7;           // batch group (8 rows)
    const int cg  = bid >> 3;          // col group (16 h-cols)

    __shared__ float gates[4][16][17];
    __shared__ unsigned short hlds[8 * HROW];   // padded 8-row h tile
    __shared__ int shBad;
    __shared__ int vals[NWG];
    __shared__ int okS;

    // ---- placement discovery: publish XCC via MALL-sentinel (no atomics) ----
    // UNBOUNDED poll (R8-exact): every WG sees all 256 publications -> all WGs
    // compute IDENTICAL vals -> identical fast/MALL decision (all-or-nothing).
    unsigned xcc;
    asm volatile("s_getreg_b32 %0, hwreg(20, 0, 4)" : "=s"(xcc));   // HW_REG_XCC_ID
    if (tid == 0) {
        okS = 1; shBad = 0;
        unsigned pv = (xcc & 15u) + 1u;            // nonzero publication
        unsigned* p = xccArr + bid;
        asm volatile("global_store_dword %0, %1, off sc0 sc1" :: "v"(p), "v"(pv) : "memory");
    }
    {   // each thread polls one WG's entry (all 256 WGs co-resident: 1 WG/CU)
        unsigned v;
        unsigned* p = xccArr + tid;
        for (;;) {
            asm volatile("global_load_dword %0, %1, off sc0 sc1" : "=&v"(v) : "v"(p));
            asm volatile("s_waitcnt vmcnt(0)" ::: "memory");
            if (v != 0u) break;
            __builtin_amdgcn_s_sleep(8);
        }
        vals[tid] = (int)(v - 1u);
    }
    __syncthreads();
    if (vals[tid] != vals[tid & 7]) atomicAnd(&okS, 0);   // group XCD-uniform
    if (tid < 8) {                                        // 8 distinct XCDs
        #pragma unroll
        for (int j = 0; j < 8; ++j)
            if (j != tid && vals[j] == vals[tid]) atomicAnd(&okS, 0);
    }
    __syncthreads();
    const bool fast = (okS != 0);

    // ---- weight slice -> registers (24 x short8 per lane) ----
    short8 bf[24];
    {
        const int gcol = w * HH + cg * 16 + nl;
        #pragma unroll
        for (int kk = 0; kk < 24; ++kk) {
            short8 v;
            #pragma unroll
            for (int j = 0; j < 8; ++j)
                v[j] = f2bf(wl[(size_t)(kk * 32 + kq * 8 + j) * 2048 + gcol]);
            bf[kk] = v;
        }
    }
    const float bias = bl[w * HH + cg * 16 + nl];

    if (fast) lstm_loop<true , PREX>(x, xs, h0, c0, out, hbuf, bf, bias, bg, cg, gates, hlds, &shBad);
    else      lstm_loop<false, PREX>(x, xs, h0, c0, out, hbuf, bf, bias, bg, cg, gates, hlds, &shBad);
}

// ---------------------------------------------------------------------------
// x[b][t][c] fp32 -> xs[t][b][c] bf16 (t-major for sequential-step locality).
// ---------------------------------------------------------------------------
__global__ void conv_x(const float* __restrict__ x, unsigned short* __restrict__ xs)
{
    const int g  = blockIdx.x * 256 + threadIdx.x;
    const int ch = g & 31;
    const int b  = (g >> 5) & 63;
    const int t  = g >> 11;
    const float* src = x + ((size_t)b * TT + t) * DIN + ch * 8;
    f32x4 lo = *(const f32x4*)src;
    f32x4 hi = *(const f32x4*)(src + 4);
    *(short8*)(xs + ((size_t)t * BB + b) * DIN + ch * 8) = pack8(lo, hi);
}

// ---------------------------------------------------------------------------
__global__ void conv_wlin(const float* __restrict__ wlin, unsigned short* __restrict__ Bt)
{
    const int g  = blockIdx.x * 256 + threadIdx.x;
    const int n  = g >> 6;
    const int kb = (g & 63) * 8;
    short8 v;
    #pragma unroll
    for (int j = 0; j < 8; ++j) v[j] = f2bf(wlin[(size_t)(kb + j) * OUTD + n]);
    *(short8*)(Bt + (size_t)n * OUTD + kb) = v;
}

// ---------------------------------------------------------------------------
__global__ __launch_bounds__(256, 2) void out_linear(
    float* __restrict__ out, const unsigned short* __restrict__ Bt, const float* __restrict__ blin)
{
    const int r0  = blockIdx.x * 32;
    const int tid = threadIdx.x;
    const int w = tid >> 6, lane = tid & 63, nl = lane & 15, kq = lane >> 4;

    __shared__ unsigned short aLds[32][520];

    {   // stage 32 rows x 512 fp32 -> bf16 LDS
        const int row = tid >> 3;
        const int cb  = (tid & 7) * 64;
        const float* src = out + (size_t)(r0 + row) * OUTD + cb;
        #pragma unroll
        for (int c = 0; c < 64; c += 4) {
            f32x4 v = *(const f32x4*)(src + c);
            aLds[row][cb + c + 0] = (unsigned short)f2bf(v[0]);
            aLds[row][cb + c + 1] = (unsigned short)f2bf(v[1]);
            aLds[row][cb + c + 2] = (unsigned short)f2bf(v[2]);
            aLds[row][cb + c + 3] = (unsigned short)f2bf(v[3]);
        }
    }
    __syncthreads();

    const f32x4 zero = {0.f, 0.f, 0.f, 0.f};
    f32x4 acc[2][8];
    #pragma unroll
    for (int m = 0; m < 2; ++m)
        #pragma unroll
        for (int n = 0; n < 8; ++n) acc[m][n] = zero;

    #pragma unroll
    for (int kk = 0; kk < 16; ++kk) {
        short8 A0 = *(const short8*)&aLds[nl][kk * 32 + kq * 8];
        short8 A1 = *(const short8*)&aLds[16 + nl][kk * 32 + kq * 8];
        #pragma unroll
        for (int n = 0; n < 8; ++n) {
            const int nt = w * 8 + n;
            short8 Bv = *(const short8*)(Bt + (size_t)(nt * 16 + nl) * OUTD + kk * 32 + kq * 8);
            acc[0][n] = MFMA(A0, Bv, acc[0][n]);
            acc[1][n] = MFMA(A1, Bv, acc[1][n]);
        }
    }

    #pragma unroll
    for (int mt = 0; mt < 2; ++mt)
        #pragma unroll
        for (int n = 0; n < 8; ++n) {
            const int col = (w * 8 + n) * 16 + nl;
            const float bb = blin[col];
            #pragma unroll
            for (int r = 0; r < 4; ++r)
                out[(size_t)(r0 + mt * 16 + kq * 4 + r) * OUTD + col] = acc[mt][n][r] + bb;
        }
}

// ---------------------------------------------------------------------------
extern "C" void kernel_launch(void* const* d_in, const int* in_sizes, int n_in,
                              void* d_out, int out_size, void* d_ws, size_t ws_size,
                              hipStream_t stream)
{
    const float* x    = (const float*)d_in[0];
    const float* h0   = (const float*)d_in[1];
    const float* c0   = (const float*)d_in[2];
    const float* wl   = (const float*)d_in[3];
    const float* bl   = (const float*)d_in[4];
    const float* wlin = (const float*)d_in[5];
    const float* blin = (const float*)d_in[6];
    float* out = (float*)d_out;

    unsigned*       xccArr = (unsigned*)d_ws;                                   // 4KB
    unsigned short* hbuf   = (unsigned short*)((char*)d_ws + 4096);             // 256KB (4 bufs)
    unsigned short* Bt     = (unsigned short*)((char*)d_ws + 4096 + 4 * BB * HH * 2);   // 512KB
    unsigned short* xs     = (unsigned short*)((char*)d_ws + 4096 + 4 * BB * HH * 2 + OUTD * OUTD * 2);

    const size_t need = 4096 + 4 * BB * HH * 2 + OUTD * OUTD * 2 + (size_t)BB * TT * DIN * 2;
    const bool prex = (ws_size >= need);

    hipMemsetAsync(d_ws, 0, 4096, stream);                 // zero xccArr
    hipMemsetAsync(hbuf, 0x7F, 4 * BB * HH * 2, stream);   // sentinel pre-fill
    conv_wlin<<<128, 256, 0, stream>>>(wlin, Bt);
    if (prex) {
        conv_x<<<(BB * TT * (DIN / 8)) / 256, 256, 0, stream>>>(x, xs);
        lstm_rec<true ><<<NWG, 256, 0, stream>>>(x, xs, h0, c0, wl, bl, out, xccArr, hbuf);
    } else {
        lstm_rec<false><<<NWG, 256, 0, stream>>>(x, xs, h0, c0, wl, bl, out, xccArr, hbuf);
    }
    out_linear<<<(BB * TT) / 32, 256, 0, stream>>>(out, Bt, blin);
}